// Round 3
// baseline (795.793 us; speedup 1.0000x reference)
//
#include <hip/hip_runtime.h>

// FeatureOctree, 3 sequential per-level passes.
// Rationale: each level's feature table is 2M x 16 f32 = 128 MB, which fits in
// the 256 MB Infinity Cache (memory-side L3). Avg reuse is 4x per corner row
// (8M samples over 2M rows), so per-level phasing converts ~75% of random
// gathers from HBM misses into L3 hits. The fused version's 384 MB combined
// working set cannot fit, giving zero reuse (measured 1.647 GB HBM ~= the
// no-reuse worst case at 3.2 TB/s random-access rate).
// 4 threads per point; lane `sub` owns float4 slice sub of the 16-dim feature.
// Stream loads (x, idx) are nontemporal to avoid evicting table lines from L3.

typedef int   v4i __attribute__((ext_vector_type(4)));

template <bool ACCUM>
__global__ __launch_bounds__(256) void octree_level_kernel(
    const float* __restrict__ x,
    const float4* __restrict__ feat,
    const int* __restrict__ idx,
    float4* __restrict__ out,
    float scale, int n_pts)
{
    long long tid = (long long)blockIdx.x * blockDim.x + threadIdx.x;
    long long pt = tid >> 2;
    int sub = (int)(tid & 3);
    if (pt >= n_pts) return;

    float xv = __builtin_nontemporal_load(x + pt * 3 + 0);
    float yv = __builtin_nontemporal_load(x + pt * 3 + 1);
    float zv = __builtin_nontemporal_load(x + pt * 3 + 2);

    float cx = scale * (xv * 0.5f + 0.5f);
    float cy = scale * (yv * 0.5f + 0.5f);
    float cz = scale * (zv * 0.5f + 0.5f);

    float dx = cx - floorf(cx);
    float dy = cy - floorf(cy);
    float dz = cz - floorf(cz);
    // t = 3d^2 - 2d^3
    float tx = dx * dx * (3.0f - 2.0f * dx);
    float ty = dy * dy * (3.0f - 2.0f * dy);
    float tz = dz * dz * (3.0f - 2.0f * dz);
    float ux = 1.0f - tx, uy = 1.0f - ty, uz = 1.0f - tz;

    float p[8];
    p[0] = ux * uy * uz;
    p[1] = ux * uy * tz;
    p[2] = ux * ty * uz;
    p[3] = ux * ty * tz;
    p[4] = tx * uy * uz;
    p[5] = tx * uy * tz;
    p[6] = tx * ty * uz;
    p[7] = tx * ty * tz;

    // idx row: 8 int32, 32B-aligned -> two nontemporal 16B loads (native vec type)
    const v4i* iv = (const v4i*)(idx + pt * 8);
    v4i ia = __builtin_nontemporal_load(iv);
    v4i ib = __builtin_nontemporal_load(iv + 1);
    int id[8] = { ia.x, ia.y, ia.z, ia.w, ib.x, ib.y, ib.z, ib.w };

    float4 acc;
    if (ACCUM) {
        acc = out[pt * 4 + sub];
    } else {
        acc = make_float4(0.f, 0.f, 0.f, 0.f);
    }

#pragma unroll
    for (int k = 0; k < 8; ++k) {
        float4 g = feat[(long long)id[k] * 4 + sub];
        acc.x = fmaf(p[k], g.x, acc.x);
        acc.y = fmaf(p[k], g.y, acc.y);
        acc.z = fmaf(p[k], g.z, acc.z);
        acc.w = fmaf(p[k], g.w, acc.w);
    }

    out[pt * 4 + sub] = acc;
}

extern "C" void kernel_launch(void* const* d_in, const int* in_sizes, int n_in,
                              void* d_out, int out_size, void* d_ws, size_t ws_size,
                              hipStream_t stream) {
    const float*  x  = (const float*)d_in[0];
    const float4* f0 = (const float4*)d_in[1];
    const float4* f1 = (const float4*)d_in[2];
    const float4* f2 = (const float4*)d_in[3];
    const int*    i0 = (const int*)d_in[4];
    const int*    i1 = (const int*)d_in[5];
    const int*    i2 = (const int*)d_in[6];
    float4* out = (float4*)d_out;

    int n_pts = in_sizes[0] / 3;
    long long total = (long long)n_pts * 4;
    int block = 256;
    int grid = (int)((total + block - 1) / block);

    // Level 12 (feat0), then 11, then 10 — sequential on the stream so each
    // pass's 128 MB table phase-occupies the L3.
    octree_level_kernel<false><<<grid, block, 0, stream>>>(x, f0, i0, out, 4096.0f, n_pts);
    octree_level_kernel<true ><<<grid, block, 0, stream>>>(x, f1, i1, out, 2048.0f, n_pts);
    octree_level_kernel<true ><<<grid, block, 0, stream>>>(x, f2, i2, out, 1024.0f, n_pts);
}